// Round 1
// baseline (1862.176 us; speedup 1.0000x reference)
//
#include <hip/hip_runtime.h>
#include <stdint.h>
#include <math.h>

#pragma clang fp contract(off)

#define NB 4
#define NN 1024
#define KNN 20
#define NT 10
#define MROWS 8

// ---------------------------------------------------------------------------
// Graph build: for each row (b,i) compute d2 to all j, select 20 smallest
// (ties by lower index, ascending order == lax.top_k of -d2), then sigma/w/s.
// ---------------------------------------------------------------------------
__global__ __launch_bounds__(256) void graph_kernel(const float* __restrict__ pc,
        int* __restrict__ idx_out, float* __restrict__ w_out, float* __restrict__ s_out){
  int row = blockIdx.x;              // b*NN + i
  int b = row >> 10, i = row & (NN-1);
  int tid = threadIdx.x;
  __shared__ float d2s[NN];
  __shared__ unsigned long long red[256];
  __shared__ int   sel_idx[KNN];
  __shared__ float sel_d2[KNN];
  const float* pb = pc + (size_t)b*NN*3;
  float xi = pb[i*3+0], yi = pb[i*3+1], zi = pb[i*3+2];
  for (int j=tid; j<NN; j+=256){
    float dx = xi - pb[j*3+0];
    float dy = yi - pb[j*3+1];
    float dz = zi - pb[j*3+2];
    float d2 = dx*dx;
    d2 = d2 + dy*dy;
    d2 = d2 + dz*dz;                 // ((dx^2+dy^2)+dz^2) like reduce over last axis
    if (j==i) d2 = d2 + 1e9f;        // + eye*1e9
    d2s[j] = d2;
  }
  __syncthreads();
  for (int k=0;k<KNN;k++){
    unsigned long long best = 0xffffffffffffffffull;
    for (int j=tid;j<NN;j+=256){
      unsigned long long key = ((unsigned long long)__float_as_uint(d2s[j])<<32) | (unsigned int)j;
      if (key < best) best = key;    // d2 >= 0 so uint bit order == float order
    }
    red[tid] = best;
    __syncthreads();
    for (int off=128; off>0; off>>=1){
      if (tid < off){ if (red[tid+off] < red[tid]) red[tid] = red[tid+off]; }
      __syncthreads();
    }
    if (tid==0){
      unsigned long long bk = red[0];
      int bj = (int)(bk & 0xffffffffu);
      sel_idx[k] = bj;
      sel_d2[k]  = __uint_as_float((unsigned int)(bk >> 32));
      d2s[bj] = __uint_as_float(0x7f800000u);  // +inf, exclude from later picks
    }
    __syncthreads();
  }
  if (tid==0){
    float dist[KNN]; float dsum = 0.0f;
    for (int k=0;k<KNN;k++){ dist[k] = sqrtf(fmaxf(sel_d2[k], 1e-12f)); dsum = dsum + dist[k]; }
    float sigma = dsum / 20.0f;          // mean
    sigma = 1.0f * sigma + 1e-6f;        // BETA*mean + EPS
    float s2 = sigma * sigma;
    float wv[KNN]; float wsum = 0.0f;
    for (int k=0;k<KNN;k++){
      float ds = dist[k]*dist[k];
      wv[k] = expf((-ds)/s2);
      wsum = wsum + wv[k];
    }
    float denom = wsum + 1e-6f;
    for (int k=0;k<KNN;k++){
      w_out[(size_t)row*KNN+k]  = wv[k] / denom;
      idx_out[(size_t)row*KNN+k] = sel_idx[k];
    }
    s_out[row] = 1.0f * sigma;           // LAM * sigma
  }
}

// ---------------------------------------------------------------------------
// Encoder: rates = clip(relu(pc @ enc_W + enc_b), 0, 1)   [B,N,64]
// ---------------------------------------------------------------------------
__global__ void enc_kernel(const float* __restrict__ pc, const float* __restrict__ W,
                           const float* __restrict__ bias, float* __restrict__ rates){
  int id = blockIdx.x*blockDim.x + threadIdx.x;
  if (id >= NB*NN*64) return;
  int f = id & 63; int bn = id >> 6;
  float p0 = pc[bn*3+0], p1 = pc[bn*3+1], p2 = pc[bn*3+2];
  float acc = fmaf(p0, W[0*64+f], 0.0f);
  acc = fmaf(p1, W[1*64+f], acc);
  acc = fmaf(p2, W[2*64+f], acc);
  acc = acc + bias[f];
  acc = fmaxf(acc, 0.0f);                    // relu
  acc = fminf(fmaxf(acc, 0.0f), 1.0f);       // clip(0,1)
  rates[id] = acc;
}

// ---------------------------------------------------------------------------
// Poisson encoding with JAX threefry2x32, key (0,42), counts iota split in half.
// u = bitcast((bits>>9)|0x3f800000) - 1 ; spike = (u < rate)
// ---------------------------------------------------------------------------
__device__ __forceinline__ uint32_t rotl32(uint32_t x, uint32_t r){ return (x<<r) | (x>>(32u-r)); }

__global__ void poisson_kernel(const float* __restrict__ rates, uint8_t* __restrict__ out){
  const uint32_t H = (uint32_t)(NB*NT*NN*64) / 2u;   // 1310720
  uint32_t i = blockIdx.x*blockDim.x + threadIdx.x;
  if (i >= H) return;
  const uint32_t ks0 = 0u, ks1 = 42u;
  const uint32_t ks2 = ks0 ^ ks1 ^ 0x1BD11BDAu;
  uint32_t x0 = i + ks0;
  uint32_t x1 = (i + H) + ks1;
#define TF4(a,b,c,d) \
  x0 += x1; x1 = rotl32(x1,a); x1 ^= x0; \
  x0 += x1; x1 = rotl32(x1,b); x1 ^= x0; \
  x0 += x1; x1 = rotl32(x1,c); x1 ^= x0; \
  x0 += x1; x1 = rotl32(x1,d); x1 ^= x0;
  TF4(13u,15u,26u,6u)  x0 += ks1; x1 += ks2 + 1u;
  TF4(17u,29u,16u,24u) x0 += ks2; x1 += ks0 + 2u;
  TF4(13u,15u,26u,6u)  x0 += ks0; x1 += ks1 + 3u;
  TF4(17u,29u,16u,24u) x0 += ks1; x1 += ks2 + 4u;
  TF4(13u,15u,26u,6u)  x0 += ks2; x1 += ks0 + 5u;
#undef TF4
  // element m=i gets x0 ; element m=i+H gets x1
  {
    uint32_t m = i;
    float u = __uint_as_float((x0 >> 9) | 0x3f800000u) - 1.0f;
    uint32_t f = m & 63u, n = (m >> 6) & (NN-1);
    uint32_t bt = m >> 16; uint32_t b = bt / NT;
    float rate = rates[(((size_t)b<<10) + n)*64 + f];
    out[m] = (u < rate) ? (uint8_t)1 : (uint8_t)0;
  }
  {
    uint32_t m = i + H;
    float u = __uint_as_float((x1 >> 9) | 0x3f800000u) - 1.0f;
    uint32_t f = m & 63u, n = (m >> 6) & (NN-1);
    uint32_t bt = m >> 16; uint32_t b = bt / NT;
    float rate = rates[(((size_t)b<<10) + n)*64 + f];
    out[m] = (u < rate) ? (uint8_t)1 : (uint8_t)0;
  }
}

// ---------------------------------------------------------------------------
// lap1: t1 = s*(x - sum_k w_k * x[idx_k])   for timestep t, x is uint8 spikes
// ---------------------------------------------------------------------------
__global__ void lap1_kernel(const uint8_t* __restrict__ x, const int* __restrict__ idx,
        const float* __restrict__ w, const float* __restrict__ s,
        float* __restrict__ t1, int t, int F){
  int bn = blockIdx.x; int f = threadIdx.x;
  int b = bn >> 10; int n = bn & (NN-1);
  __shared__ int nidx[KNN]; __shared__ float nw[KNN]; __shared__ float sv;
  if (f < KNN){ nidx[f] = idx[(size_t)bn*KNN+f]; nw[f] = w[(size_t)bn*KNN+f]; }
  if (f == 0) sv = s[bn];
  __syncthreads();
  const uint8_t* xb = x + ((size_t)(b*NT + t)*NN)*F;
  float acc = 0.0f;
  for (int k=0;k<KNN;k++)
    acc = fmaf(nw[k], (float)xb[(size_t)nidx[k]*F + f], acc);
  float xv = (float)xb[(size_t)n*F + f];
  t1[(size_t)bn*F + f] = sv * (xv - acc);
}

// ---------------------------------------------------------------------------
// lap2: t2 = 2*(s*(t1 - sum_k w_k * t1[idx_k])) - x
// ---------------------------------------------------------------------------
__global__ void lap2_kernel(const uint8_t* __restrict__ x, const float* __restrict__ t1,
        const int* __restrict__ idx, const float* __restrict__ w, const float* __restrict__ s,
        float* __restrict__ t2, int t, int F){
  int bn = blockIdx.x; int f = threadIdx.x;
  int b = bn >> 10; int n = bn & (NN-1);
  __shared__ int nidx[KNN]; __shared__ float nw[KNN]; __shared__ float sv;
  if (f < KNN){ nidx[f] = idx[(size_t)bn*KNN+f]; nw[f] = w[(size_t)bn*KNN+f]; }
  if (f == 0) sv = s[bn];
  __syncthreads();
  const float* t1b = t1 + ((size_t)b*NN)*F;
  float acc = 0.0f;
  for (int k=0;k<KNN;k++)
    acc = fmaf(nw[k], t1b[(size_t)nidx[k]*F + f], acc);
  float tv = t1[(size_t)bn*F + f];
  float lapv = sv * (tv - acc);
  const uint8_t* xb = x + ((size_t)(b*NT + t)*NN)*F;
  float xv = (float)xb[(size_t)n*F + f];
  t2[(size_t)bn*F + f] = 2.0f * lapv - xv;
}

// ---------------------------------------------------------------------------
// conv (Chebyshev K=3, k-major f-minor sequential fma) + bias + LIF step.
// Processes MROWS nodes per block to reuse W through registers/LDS.
// ---------------------------------------------------------------------------
__global__ void conv_lif_kernel(const uint8_t* __restrict__ x, const float* __restrict__ t1,
        const float* __restrict__ t2, const float* __restrict__ W, const float* __restrict__ bias,
        float* __restrict__ v, uint8_t* __restrict__ out, int t, int F, int G, float decay){
  int g = threadIdx.x;
  int bn0 = blockIdx.x * MROWS;
  extern __shared__ float smem[];                 // [3][MROWS][F]
  float* s0 = smem;
  float* s1 = smem + (size_t)MROWS*F;
  float* s2 = smem + (size_t)2*MROWS*F;
  for (int r=0;r<MROWS;r++){
    int bn = bn0 + r;
    int b = bn >> 10, n = bn & (NN-1);
    const uint8_t* xb  = x  + ((size_t)(b*NT+t)*NN + n)*F;
    const float*   t1b = t1 + (size_t)bn*F;
    const float*   t2b = t2 + (size_t)bn*F;
    for (int f=g; f<F; f+=G){
      s0[r*F+f] = (float)xb[f];
      s1[r*F+f] = t1b[f];
      s2[r*F+f] = t2b[f];
    }
  }
  __syncthreads();
  float acc[MROWS];
  #pragma unroll
  for (int r=0;r<MROWS;r++) acc[r] = 0.0f;
  const float* W0 = W;
  const float* W1 = W + (size_t)F*G;
  const float* W2 = W + (size_t)2*F*G;
  for (int f=0; f<F; f++){
    float wv = W0[f*G + g];
    #pragma unroll
    for (int r=0;r<MROWS;r++) acc[r] = fmaf(s0[r*F+f], wv, acc[r]);
  }
  for (int f=0; f<F; f++){
    float wv = W1[f*G + g];
    #pragma unroll
    for (int r=0;r<MROWS;r++) acc[r] = fmaf(s1[r*F+f], wv, acc[r]);
  }
  for (int f=0; f<F; f++){
    float wv = W2[f*G + g];
    #pragma unroll
    for (int r=0;r<MROWS;r++) acc[r] = fmaf(s2[r*F+f], wv, acc[r]);
  }
  float bg = bias[g];
  for (int r=0;r<MROWS;r++){
    int bn = bn0 + r;
    int b = bn >> 10, n = bn & (NN-1);
    float a = acc[r] + bg;
    size_t vi = (size_t)bn*G + g;
    float vn = decay * v[vi] + a;                 // contract(off): mul then add
    float sp  = ((vn - 1.0f) >= 0.0f) ? 1.0f : 0.0f;   // spike(v - TH_POS)
    float snk = ((-1.0f - vn) >= 0.0f) ? 1.0f : 0.0f;  // spike(TH_NEG - v)
    vn = vn - sp * 1.0f;                          // - sp*TH_POS
    vn = vn - snk * (-1.0f);                      // - sn*TH_NEG
    v[vi] = vn;
    uint8_t* ob = out + ((size_t)(b*NT+t)*NN + n)*((size_t)2*G);
    ob[g]   = (uint8_t)sp;
    ob[G+g] = (uint8_t)snk;
  }
}

// ---------------------------------------------------------------------------
// pooled[b,f] = mean_n( mean_t spikes[b,t,n,f] )   spikes width 512
// ---------------------------------------------------------------------------
__global__ void pool_kernel(const uint8_t* __restrict__ sp, float* __restrict__ pooled){
  int id = blockIdx.x*blockDim.x + threadIdx.x;   // B*512
  if (id >= NB*512) return;
  int b = id >> 9; int f = id & 511;
  float accN = 0.0f;
  for (int n=0;n<NN;n++){
    float at = 0.0f;
    for (int tt=0;tt<NT;tt++)
      at = at + (float)sp[((size_t)(b*NT+tt)*NN + n)*512 + f];
    accN = accN + at / 10.0f;
  }
  pooled[id] = accN / 1024.0f;
}

// out[b,c] = pooled[b,:] @ ro_W + ro_b
__global__ void head_kernel(const float* __restrict__ pooled, const float* __restrict__ roW,
                            const float* __restrict__ rob, float* __restrict__ out){
  int id = blockIdx.x*blockDim.x + threadIdx.x;   // B*40
  if (id >= NB*40) return;
  int b = id / 40; int c = id % 40;
  float acc = 0.0f;
  for (int f=0; f<512; f++)
    acc = fmaf(pooled[b*512+f], roW[f*40+c], acc);
  out[id] = acc + rob[c];
}

// ---------------------------------------------------------------------------
extern "C" void kernel_launch(void* const* d_in, const int* in_sizes, int n_in,
                              void* d_out, int out_size, void* d_ws, size_t ws_size,
                              hipStream_t stream) {
  const float* pc   = (const float*)d_in[0];
  const float* encW = (const float*)d_in[1];
  const float* encB = (const float*)d_in[2];
  const float* W0   = (const float*)d_in[3];
  const float* b0   = (const float*)d_in[4];
  const float* W1   = (const float*)d_in[5];
  const float* b1   = (const float*)d_in[6];
  const float* W2   = (const float*)d_in[7];
  const float* b2   = (const float*)d_in[8];
  const float* roW  = (const float*)d_in[9];
  const float* rob  = (const float*)d_in[10];
  float* outp = (float*)d_out;

  char* p = (char*)d_ws;
  auto alloc = [&](size_t bytes)->char*{
    char* r = p; p += (bytes + 255) & ~(size_t)255; return r;
  };
  int*     idxb  = (int*)  alloc((size_t)NB*NN*KNN*4);
  float*   wb    = (float*)alloc((size_t)NB*NN*KNN*4);
  float*   sb    = (float*)alloc((size_t)NB*NN*4);
  float*   rates = (float*)alloc((size_t)NB*NN*64*4);
  float*   t1b   = (float*)alloc((size_t)NB*NN*256*4);
  float*   t2b   = (float*)alloc((size_t)NB*NN*256*4);
  float*   vb    = (float*)alloc((size_t)NB*NN*256*4);
  float*   pooled= (float*)alloc((size_t)NB*512*4);
  uint8_t* bufA  = (uint8_t*)alloc((size_t)NB*NT*NN*512);
  uint8_t* bufB  = (uint8_t*)alloc((size_t)NB*NT*NN*512);

  // 1. graph
  graph_kernel<<<NB*NN, 256, 0, stream>>>(pc, idxb, wb, sb);
  // 2. encoder rates
  enc_kernel<<<(NB*NN*64 + 255)/256, 256, 0, stream>>>(pc, encW, encB, rates);
  // 3. poisson spikes -> bufA width 64
  {
    const uint32_t H = (uint32_t)(NB*NT*NN*64) / 2u;
    poisson_kernel<<<(H + 255)/256, 256, 0, stream>>>(rates, bufA);
  }

  float decay = expf(-1.0f / 20.0f);

  struct Layer { int F, G; const float* W; const float* bias; };
  Layer Ls[3] = { {64,64,W0,b0}, {128,128,W1,b1}, {256,256,W2,b2} };

  uint8_t* xin  = bufA;
  uint8_t* xout = bufB;
  for (int l=0; l<3; l++){
    int F = Ls[l].F, G = Ls[l].G;
    hipMemsetAsync(vb, 0, (size_t)NB*NN*G*4, stream);
    size_t convLds = (size_t)3*MROWS*F*4;
    for (int t=0; t<NT; t++){
      lap1_kernel<<<NB*NN, F, 0, stream>>>(xin, idxb, wb, sb, t1b, t, F);
      lap2_kernel<<<NB*NN, F, 0, stream>>>(xin, t1b, idxb, wb, sb, t2b, t, F);
      conv_lif_kernel<<<(NB*NN)/MROWS, G, convLds, stream>>>(
          xin, t1b, t2b, Ls[l].W, Ls[l].bias, vb, xout, t, F, G, decay);
    }
    uint8_t* tmp = xin; xin = xout; xout = tmp;
  }

  // xin now holds final spikes [B,T,N,512]
  pool_kernel<<<(NB*512 + 255)/256, 256, 0, stream>>>(xin, pooled);
  head_kernel<<<(NB*40 + 63)/64, 64, 0, stream>>>(pooled, roW, rob, outp);
}

// Round 2
// 937.869 us; speedup vs baseline: 1.9855x; 1.9855x over previous
//
#include <hip/hip_runtime.h>
#include <stdint.h>
#include <math.h>

#pragma clang fp contract(off)

#define NB 4
#define NN 1024
#define KNN 20
#define NT 10
#define MROWS 8

// ---------------------------------------------------------------------------
// Graph build: for each row (b,i) compute d2 to all j, select 20 smallest
// (ties by lower index, ascending order == lax.top_k of -d2), then sigma/w/s.
// ---------------------------------------------------------------------------
__global__ __launch_bounds__(256) void graph_kernel(const float* __restrict__ pc,
        int* __restrict__ idx_out, float* __restrict__ w_out, float* __restrict__ s_out){
  int row = blockIdx.x;              // b*NN + i
  int b = row >> 10, i = row & (NN-1);
  int tid = threadIdx.x;
  __shared__ float d2s[NN];
  __shared__ unsigned long long red[256];
  __shared__ int   sel_idx[KNN];
  __shared__ float sel_d2[KNN];
  const float* pb = pc + (size_t)b*NN*3;
  float xi = pb[i*3+0], yi = pb[i*3+1], zi = pb[i*3+2];
  for (int j=tid; j<NN; j+=256){
    float dx = xi - pb[j*3+0];
    float dy = yi - pb[j*3+1];
    float dz = zi - pb[j*3+2];
    float d2 = dx*dx;
    d2 = d2 + dy*dy;
    d2 = d2 + dz*dz;
    if (j==i) d2 = d2 + 1e9f;
    d2s[j] = d2;
  }
  __syncthreads();
  for (int k=0;k<KNN;k++){
    unsigned long long best = 0xffffffffffffffffull;
    for (int j=tid;j<NN;j+=256){
      unsigned long long key = ((unsigned long long)__float_as_uint(d2s[j])<<32) | (unsigned int)j;
      if (key < best) best = key;
    }
    red[tid] = best;
    __syncthreads();
    for (int off=128; off>0; off>>=1){
      if (tid < off){ if (red[tid+off] < red[tid]) red[tid] = red[tid+off]; }
      __syncthreads();
    }
    if (tid==0){
      unsigned long long bk = red[0];
      int bj = (int)(bk & 0xffffffffu);
      sel_idx[k] = bj;
      sel_d2[k]  = __uint_as_float((unsigned int)(bk >> 32));
      d2s[bj] = __uint_as_float(0x7f800000u);
    }
    __syncthreads();
  }
  if (tid==0){
    float dist[KNN]; float dsum = 0.0f;
    for (int k=0;k<KNN;k++){ dist[k] = sqrtf(fmaxf(sel_d2[k], 1e-12f)); dsum = dsum + dist[k]; }
    float sigma = dsum / 20.0f;
    sigma = 1.0f * sigma + 1e-6f;
    float s2 = sigma * sigma;
    float wv[KNN]; float wsum = 0.0f;
    for (int k=0;k<KNN;k++){
      float ds = dist[k]*dist[k];
      wv[k] = expf((-ds)/s2);
      wsum = wsum + wv[k];
    }
    float denom = wsum + 1e-6f;
    for (int k=0;k<KNN;k++){
      w_out[(size_t)row*KNN+k]  = wv[k] / denom;
      idx_out[(size_t)row*KNN+k] = sel_idx[k];
    }
    s_out[row] = 1.0f * sigma;
  }
}

// ---------------------------------------------------------------------------
// Encoder: rates = clip(relu(pc @ enc_W + enc_b), 0, 1)   [B,N,64]
// ---------------------------------------------------------------------------
__global__ void enc_kernel(const float* __restrict__ pc, const float* __restrict__ W,
                           const float* __restrict__ bias, float* __restrict__ rates){
  int id = blockIdx.x*blockDim.x + threadIdx.x;
  if (id >= NB*NN*64) return;
  int f = id & 63; int bn = id >> 6;
  float p0 = pc[bn*3+0], p1 = pc[bn*3+1], p2 = pc[bn*3+2];
  float acc = fmaf(p0, W[0*64+f], 0.0f);
  acc = fmaf(p1, W[1*64+f], acc);
  acc = fmaf(p2, W[2*64+f], acc);
  acc = acc + bias[f];
  acc = fmaxf(acc, 0.0f);
  acc = fminf(fmaxf(acc, 0.0f), 1.0f);
  rates[id] = acc;
}

// ---------------------------------------------------------------------------
// Poisson encoding with JAX threefry2x32, key (0,42), counts iota split in half.
// ---------------------------------------------------------------------------
__device__ __forceinline__ uint32_t rotl32(uint32_t x, uint32_t r){ return (x<<r) | (x>>(32u-r)); }

__global__ void poisson_kernel(const float* __restrict__ rates, uint8_t* __restrict__ out){
  const uint32_t H = (uint32_t)(NB*NT*NN*64) / 2u;
  uint32_t i = blockIdx.x*blockDim.x + threadIdx.x;
  if (i >= H) return;
  const uint32_t ks0 = 0u, ks1 = 42u;
  const uint32_t ks2 = ks0 ^ ks1 ^ 0x1BD11BDAu;
  uint32_t x0 = i + ks0;
  uint32_t x1 = (i + H) + ks1;
#define TF4(a,b,c,d) \
  x0 += x1; x1 = rotl32(x1,a); x1 ^= x0; \
  x0 += x1; x1 = rotl32(x1,b); x1 ^= x0; \
  x0 += x1; x1 = rotl32(x1,c); x1 ^= x0; \
  x0 += x1; x1 = rotl32(x1,d); x1 ^= x0;
  TF4(13u,15u,26u,6u)  x0 += ks1; x1 += ks2 + 1u;
  TF4(17u,29u,16u,24u) x0 += ks2; x1 += ks0 + 2u;
  TF4(13u,15u,26u,6u)  x0 += ks0; x1 += ks1 + 3u;
  TF4(17u,29u,16u,24u) x0 += ks1; x1 += ks2 + 4u;
  TF4(13u,15u,26u,6u)  x0 += ks2; x1 += ks0 + 5u;
#undef TF4
  {
    uint32_t m = i;
    float u = __uint_as_float((x0 >> 9) | 0x3f800000u) - 1.0f;
    uint32_t f = m & 63u, n = (m >> 6) & (NN-1);
    uint32_t bt = m >> 16; uint32_t b = bt / NT;
    float rate = rates[(((size_t)b<<10) + n)*64 + f];
    out[m] = (u < rate) ? (uint8_t)1 : (uint8_t)0;
  }
  {
    uint32_t m = i + H;
    float u = __uint_as_float((x1 >> 9) | 0x3f800000u) - 1.0f;
    uint32_t f = m & 63u, n = (m >> 6) & (NN-1);
    uint32_t bt = m >> 16; uint32_t b = bt / NT;
    float rate = rates[(((size_t)b<<10) + n)*64 + f];
    out[m] = (u < rate) ? (uint8_t)1 : (uint8_t)0;
  }
}

// ---------------------------------------------------------------------------
// lap1 over a chunk of timesteps: grid = NB*NN*tc blocks, blockDim = F.
// t1[tt][bn][f] = s*(x - sum_k w_k x[idx_k])  at global timestep t0+tt
// ---------------------------------------------------------------------------
__global__ void lap1_all_kernel(const uint8_t* __restrict__ x, const int* __restrict__ idx,
        const float* __restrict__ w, const float* __restrict__ s,
        float* __restrict__ t1, int t0, int F){
  int blk = blockIdx.x; int f = threadIdx.x;
  int bn = blk % (NB*NN); int tt = blk / (NB*NN);
  int b = bn >> 10; int n = bn & (NN-1); int t = t0 + tt;
  __shared__ int nidx[KNN]; __shared__ float nw[KNN]; __shared__ float sv;
  if (f < KNN){ nidx[f] = idx[(size_t)bn*KNN+f]; nw[f] = w[(size_t)bn*KNN+f]; }
  if (f == 0) sv = s[bn];
  __syncthreads();
  const uint8_t* xb = x + ((size_t)(b*NT + t)*NN)*F;
  float acc = 0.0f;
  for (int k=0;k<KNN;k++)
    acc = fmaf(nw[k], (float)xb[(size_t)nidx[k]*F + f], acc);
  float xv = (float)xb[(size_t)n*F + f];
  t1[((size_t)tt*(NB*NN) + bn)*F + f] = sv * (xv - acc);
}

// ---------------------------------------------------------------------------
// lap2: t2 = 2*(s*(t1 - sum_k w_k t1[idx_k])) - x
// ---------------------------------------------------------------------------
__global__ void lap2_all_kernel(const uint8_t* __restrict__ x, const float* __restrict__ t1,
        const int* __restrict__ idx, const float* __restrict__ w, const float* __restrict__ s,
        float* __restrict__ t2, int t0, int F){
  int blk = blockIdx.x; int f = threadIdx.x;
  int bn = blk % (NB*NN); int tt = blk / (NB*NN);
  int b = bn >> 10; int n = bn & (NN-1); int t = t0 + tt;
  __shared__ int nidx[KNN]; __shared__ float nw[KNN]; __shared__ float sv;
  if (f < KNN){ nidx[f] = idx[(size_t)bn*KNN+f]; nw[f] = w[(size_t)bn*KNN+f]; }
  if (f == 0) sv = s[bn];
  __syncthreads();
  const float* t1b = t1 + ((size_t)tt*(NB*NN) + (size_t)b*NN)*F;
  float acc = 0.0f;
  for (int k=0;k<KNN;k++)
    acc = fmaf(nw[k], t1b[(size_t)nidx[k]*F + f], acc);
  float tv = t1[((size_t)tt*(NB*NN) + bn)*F + f];
  float lapv = sv * (tv - acc);
  const uint8_t* xb = x + ((size_t)(b*NT + t)*NN)*F;
  float xv = (float)xb[(size_t)n*F + f];
  t2[((size_t)tt*(NB*NN) + bn)*F + f] = 2.0f * lapv - xv;
}

// ---------------------------------------------------------------------------
// Fused Chebyshev conv + bias + LIF over a chunk of timesteps.
// Block = 256 threads = YR row-groups x G outputs; MROWS rows per block total.
// v kept in registers across the whole chunk. Bit-identical fma chain per output.
// ---------------------------------------------------------------------------
template<int F, int G, int MPY>
__global__ __launch_bounds__(256) void conv_lif_all_kernel(const uint8_t* __restrict__ x,
        const float* __restrict__ t1, const float* __restrict__ t2,
        const float* __restrict__ W, const float* __restrict__ bias,
        float* __restrict__ vbuf, uint8_t* __restrict__ out,
        int t0, int tc, float decay){
  int tid = threadIdx.x;
  int g = tid % G;
  int y = tid / G;
  int r0 = y * MPY;
  int bn0 = blockIdx.x * MROWS;
  __shared__ float smem[3*MROWS*F];
  float* s0 = smem;
  float* s1 = smem + MROWS*F;
  float* s2 = smem + 2*MROWS*F;

  float v[MPY];
  #pragma unroll
  for (int j=0;j<MPY;j++)
    v[j] = (t0 == 0) ? 0.0f : vbuf[(size_t)(bn0 + r0 + j)*G + g];
  float bg = bias[g];
  const float* W0 = W;
  const float* W1 = W + (size_t)F*G;
  const float* W2 = W + (size_t)2*F*G;

  for (int tt=0; tt<tc; ++tt){
    int t = t0 + tt;
    for (int e=tid; e<MROWS*F; e+=256){
      int r = e / F, f = e % F;
      int bn = bn0 + r; int b = bn >> 10, n = bn & (NN-1);
      s0[e] = (float)x[((size_t)(b*NT+t)*NN + n)*F + f];
      size_t tb = ((size_t)tt*(NB*NN) + bn)*F + f;
      s1[e] = t1[tb];
      s2[e] = t2[tb];
    }
    __syncthreads();

    float acc[MPY];
    #pragma unroll
    for (int j=0;j<MPY;j++) acc[j] = 0.0f;
    for (int f=0; f<F; f++){
      float wv = W0[f*G + g];
      #pragma unroll
      for (int j=0;j<MPY;j++) acc[j] = fmaf(s0[(r0+j)*F+f], wv, acc[j]);
    }
    for (int f=0; f<F; f++){
      float wv = W1[f*G + g];
      #pragma unroll
      for (int j=0;j<MPY;j++) acc[j] = fmaf(s1[(r0+j)*F+f], wv, acc[j]);
    }
    for (int f=0; f<F; f++){
      float wv = W2[f*G + g];
      #pragma unroll
      for (int j=0;j<MPY;j++) acc[j] = fmaf(s2[(r0+j)*F+f], wv, acc[j]);
    }

    #pragma unroll
    for (int j=0;j<MPY;j++){
      int bn = bn0 + r0 + j;
      int b = bn >> 10, n = bn & (NN-1);
      float a = acc[j] + bg;
      float vn = decay * v[j] + a;
      float sp  = ((vn - 1.0f) >= 0.0f) ? 1.0f : 0.0f;
      float snk = ((-1.0f - vn) >= 0.0f) ? 1.0f : 0.0f;
      vn = vn - sp * 1.0f;
      vn = vn - snk * (-1.0f);
      v[j] = vn;
      uint8_t* ob = out + ((size_t)(b*NT+t)*NN + n)*((size_t)2*G);
      ob[g]   = (uint8_t)sp;
      ob[G+g] = (uint8_t)snk;
    }
    __syncthreads();
  }
  if (t0 + tc < NT){
    #pragma unroll
    for (int j=0;j<MPY;j++)
      vbuf[(size_t)(bn0 + r0 + j)*G + g] = v[j];
  }
}

// ---------------------------------------------------------------------------
// Pool stage 1: integer spike counts. grid = NB*64 blocks (16 nodes each),
// 128 threads (one uint32 = 4 f-columns each). Exact, order-independent.
// ---------------------------------------------------------------------------
__global__ void pool_partial_kernel(const uint8_t* __restrict__ sp, uint32_t* __restrict__ partial){
  int b = blockIdx.x >> 6;
  int chunk = blockIdx.x & 63;
  int n0 = chunk * 16;
  int u = threadIdx.x;                      // 0..127
  uint32_t c0=0,c1=0,c2=0,c3=0;
  for (int t=0;t<NT;t++){
    for (int n=0;n<16;n++){
      const uint32_t* rowp = (const uint32_t*)(sp + ((size_t)(b*NT+t)*NN + n0+n)*512);
      uint32_t wv = rowp[u];
      c0 += wv & 0xffu;
      c1 += (wv >> 8) & 0xffu;
      c2 += (wv >> 16) & 0xffu;
      c3 += wv >> 24;
    }
  }
  uint32_t* op = partial + (size_t)blockIdx.x*512 + u*4;
  op[0]=c0; op[1]=c1; op[2]=c2; op[3]=c3;
}

// ---------------------------------------------------------------------------
// Pool finalize + head. One block per batch, 512 threads.
// pooled[f] = total_count / 10 / 1024 ; out = pooled @ ro_W + ro_b
// ---------------------------------------------------------------------------
__global__ __launch_bounds__(512) void finalize_head_kernel(const uint32_t* __restrict__ partial,
        const float* __restrict__ roW, const float* __restrict__ rob, float* __restrict__ out){
  int b = blockIdx.x;
  int f = threadIdx.x;
  __shared__ float pooled[512];
  uint32_t cnt = 0;
  for (int ch=0; ch<64; ch++)
    cnt += partial[((size_t)(b*64+ch))*512 + f];
  pooled[f] = (float)cnt / 10.0f / 1024.0f;
  __syncthreads();
  if (f < 40){
    float acc = 0.0f;
    for (int k=0;k<512;k++)
      acc = fmaf(pooled[k], roW[k*40+f], acc);
    out[b*40 + f] = acc + rob[f];
  }
}

// ---------------------------------------------------------------------------
extern "C" void kernel_launch(void* const* d_in, const int* in_sizes, int n_in,
                              void* d_out, int out_size, void* d_ws, size_t ws_size,
                              hipStream_t stream) {
  const float* pc   = (const float*)d_in[0];
  const float* encW = (const float*)d_in[1];
  const float* encB = (const float*)d_in[2];
  const float* W0   = (const float*)d_in[3];
  const float* b0   = (const float*)d_in[4];
  const float* W1   = (const float*)d_in[5];
  const float* b1   = (const float*)d_in[6];
  const float* W2   = (const float*)d_in[7];
  const float* b2   = (const float*)d_in[8];
  const float* roW  = (const float*)d_in[9];
  const float* rob  = (const float*)d_in[10];
  float* outp = (float*)d_out;

  char* p = (char*)d_ws;
  auto alloc = [&](size_t bytes)->char*{
    char* r = p; p += (bytes + 255) & ~(size_t)255; return r;
  };
  int*      idxb   = (int*)     alloc((size_t)NB*NN*KNN*4);
  float*    wb     = (float*)   alloc((size_t)NB*NN*KNN*4);
  float*    sb     = (float*)   alloc((size_t)NB*NN*4);
  float*    rates  = (float*)   alloc((size_t)NB*NN*64*4);
  float*    vbuf   = (float*)   alloc((size_t)NB*NN*256*4);
  uint32_t* partial= (uint32_t*)alloc((size_t)NB*64*512*4);
  uint8_t*  bufA   = (uint8_t*) alloc((size_t)NB*NT*NN*512);
  uint8_t*  bufB   = (uint8_t*) alloc((size_t)NB*NT*NN*512);

  // timestep chunking so t1/t2 fit in whatever workspace remains
  size_t used = (size_t)(p - (char*)d_ws);
  size_t per_t = (size_t)NB*NN*256*4*2;      // t1+t2 for one timestep (worst F=256)
  int TC = 1;
  if (ws_size > used + per_t){
    size_t tcc = (ws_size - used) / per_t;
    TC = (tcc >= NT) ? NT : (int)tcc;
    if (TC < 1) TC = 1;
  }
  float* t1b = (float*)alloc((size_t)NB*(size_t)TC*NN*256*4);
  float* t2b = (float*)alloc((size_t)NB*(size_t)TC*NN*256*4);

  graph_kernel<<<NB*NN, 256, 0, stream>>>(pc, idxb, wb, sb);
  enc_kernel<<<(NB*NN*64 + 255)/256, 256, 0, stream>>>(pc, encW, encB, rates);
  {
    const uint32_t H = (uint32_t)(NB*NT*NN*64) / 2u;
    poisson_kernel<<<(H + 255)/256, 256, 0, stream>>>(rates, bufA);
  }

  float decay = expf(-1.0f / 20.0f);

  uint8_t* xin  = bufA;
  uint8_t* xout = bufB;
  for (int l=0; l<3; l++){
    int F = (l==0)?64:(l==1)?128:256;
    const float* Wc = (l==0)?W0:(l==1)?W1:W2;
    const float* bc = (l==0)?b0:(l==1)?b1:b2;
    for (int t0=0; t0<NT; t0+=TC){
      int tc = (NT - t0 < TC) ? (NT - t0) : TC;
      lap1_all_kernel<<<NB*NN*tc, F, 0, stream>>>(xin, idxb, wb, sb, t1b, t0, F);
      lap2_all_kernel<<<NB*NN*tc, F, 0, stream>>>(xin, t1b, idxb, wb, sb, t2b, t0, F);
      int grid = (NB*NN)/MROWS;
      if (l==0)
        conv_lif_all_kernel<64,64,2><<<grid, 256, 0, stream>>>(xin, t1b, t2b, Wc, bc, vbuf, xout, t0, tc, decay);
      else if (l==1)
        conv_lif_all_kernel<128,128,4><<<grid, 256, 0, stream>>>(xin, t1b, t2b, Wc, bc, vbuf, xout, t0, tc, decay);
      else
        conv_lif_all_kernel<256,256,8><<<grid, 256, 0, stream>>>(xin, t1b, t2b, Wc, bc, vbuf, xout, t0, tc, decay);
    }
    uint8_t* tmp = xin; xin = xout; xout = tmp;
  }

  // xin holds final spikes [B,T,N,512]
  pool_partial_kernel<<<NB*64, 128, 0, stream>>>(xin, partial);
  finalize_head_kernel<<<NB, 512, 0, stream>>>(partial, roW, rob, outp);
}

// Round 3
// 549.306 us; speedup vs baseline: 3.3901x; 1.7074x over previous
//
#include <hip/hip_runtime.h>
#include <stdint.h>
#include <math.h>

#pragma clang fp contract(off)

#define NB 4
#define NN 1024
#define KNN 20
#define NT 10

// ---------------------------------------------------------------------------
// Graph build
// ---------------------------------------------------------------------------
__global__ __launch_bounds__(256) void graph_kernel(const float* __restrict__ pc,
        int* __restrict__ idx_out, float* __restrict__ w_out, float* __restrict__ s_out){
  int row = blockIdx.x;              // b*NN + i
  int b = row >> 10, i = row & (NN-1);
  int tid = threadIdx.x;
  __shared__ float d2s[NN];
  __shared__ unsigned long long red[256];
  __shared__ int   sel_idx[KNN];
  __shared__ float sel_d2[KNN];
  const float* pb = pc + (size_t)b*NN*3;
  float xi = pb[i*3+0], yi = pb[i*3+1], zi = pb[i*3+2];
  for (int j=tid; j<NN; j+=256){
    float dx = xi - pb[j*3+0];
    float dy = yi - pb[j*3+1];
    float dz = zi - pb[j*3+2];
    float d2 = dx*dx;
    d2 = d2 + dy*dy;
    d2 = d2 + dz*dz;
    if (j==i) d2 = d2 + 1e9f;
    d2s[j] = d2;
  }
  __syncthreads();
  for (int k=0;k<KNN;k++){
    unsigned long long best = 0xffffffffffffffffull;
    for (int j=tid;j<NN;j+=256){
      unsigned long long key = ((unsigned long long)__float_as_uint(d2s[j])<<32) | (unsigned int)j;
      if (key < best) best = key;
    }
    red[tid] = best;
    __syncthreads();
    for (int off=128; off>0; off>>=1){
      if (tid < off){ if (red[tid+off] < red[tid]) red[tid] = red[tid+off]; }
      __syncthreads();
    }
    if (tid==0){
      unsigned long long bk = red[0];
      int bj = (int)(bk & 0xffffffffu);
      sel_idx[k] = bj;
      sel_d2[k]  = __uint_as_float((unsigned int)(bk >> 32));
      d2s[bj] = __uint_as_float(0x7f800000u);
    }
    __syncthreads();
  }
  if (tid==0){
    float dist[KNN]; float dsum = 0.0f;
    for (int k=0;k<KNN;k++){ dist[k] = sqrtf(fmaxf(sel_d2[k], 1e-12f)); dsum = dsum + dist[k]; }
    float sigma = dsum / 20.0f;
    sigma = 1.0f * sigma + 1e-6f;
    float s2 = sigma * sigma;
    float wv[KNN]; float wsum = 0.0f;
    for (int k=0;k<KNN;k++){
      float ds = dist[k]*dist[k];
      wv[k] = expf((-ds)/s2);
      wsum = wsum + wv[k];
    }
    float denom = wsum + 1e-6f;
    for (int k=0;k<KNN;k++){
      w_out[(size_t)row*KNN+k]  = wv[k] / denom;
      idx_out[(size_t)row*KNN+k] = sel_idx[k];
    }
    s_out[row] = 1.0f * sigma;
  }
}

// ---------------------------------------------------------------------------
// Encoder
// ---------------------------------------------------------------------------
__global__ void enc_kernel(const float* __restrict__ pc, const float* __restrict__ W,
                           const float* __restrict__ bias, float* __restrict__ rates){
  int id = blockIdx.x*blockDim.x + threadIdx.x;
  if (id >= NB*NN*64) return;
  int f = id & 63; int bn = id >> 6;
  float p0 = pc[bn*3+0], p1 = pc[bn*3+1], p2 = pc[bn*3+2];
  float acc = fmaf(p0, W[0*64+f], 0.0f);
  acc = fmaf(p1, W[1*64+f], acc);
  acc = fmaf(p2, W[2*64+f], acc);
  acc = acc + bias[f];
  acc = fmaxf(acc, 0.0f);
  acc = fminf(fmaxf(acc, 0.0f), 1.0f);
  rates[id] = acc;
}

// ---------------------------------------------------------------------------
// Poisson encoding (JAX threefry2x32, key (0,42))
// ---------------------------------------------------------------------------
__device__ __forceinline__ uint32_t rotl32(uint32_t x, uint32_t r){ return (x<<r) | (x>>(32u-r)); }

__global__ void poisson_kernel(const float* __restrict__ rates, uint8_t* __restrict__ out){
  const uint32_t H = (uint32_t)(NB*NT*NN*64) / 2u;
  uint32_t i = blockIdx.x*blockDim.x + threadIdx.x;
  if (i >= H) return;
  const uint32_t ks0 = 0u, ks1 = 42u;
  const uint32_t ks2 = ks0 ^ ks1 ^ 0x1BD11BDAu;
  uint32_t x0 = i + ks0;
  uint32_t x1 = (i + H) + ks1;
#define TF4(a,b,c,d) \
  x0 += x1; x1 = rotl32(x1,a); x1 ^= x0; \
  x0 += x1; x1 = rotl32(x1,b); x1 ^= x0; \
  x0 += x1; x1 = rotl32(x1,c); x1 ^= x0; \
  x0 += x1; x1 = rotl32(x1,d); x1 ^= x0;
  TF4(13u,15u,26u,6u)  x0 += ks1; x1 += ks2 + 1u;
  TF4(17u,29u,16u,24u) x0 += ks2; x1 += ks0 + 2u;
  TF4(13u,15u,26u,6u)  x0 += ks0; x1 += ks1 + 3u;
  TF4(17u,29u,16u,24u) x0 += ks1; x1 += ks2 + 4u;
  TF4(13u,15u,26u,6u)  x0 += ks2; x1 += ks0 + 5u;
#undef TF4
  {
    uint32_t m = i;
    float u = __uint_as_float((x0 >> 9) | 0x3f800000u) - 1.0f;
    uint32_t f = m & 63u, n = (m >> 6) & (NN-1);
    uint32_t bt = m >> 16; uint32_t b = bt / NT;
    float rate = rates[(((size_t)b<<10) + n)*64 + f];
    out[m] = (u < rate) ? (uint8_t)1 : (uint8_t)0;
  }
  {
    uint32_t m = i + H;
    float u = __uint_as_float((x1 >> 9) | 0x3f800000u) - 1.0f;
    uint32_t f = m & 63u, n = (m >> 6) & (NN-1);
    uint32_t bt = m >> 16; uint32_t b = bt / NT;
    float rate = rates[(((size_t)b<<10) + n)*64 + f];
    out[m] = (u < rate) ? (uint8_t)1 : (uint8_t)0;
  }
}

// ---------------------------------------------------------------------------
// lap1 over chunk: t1[tt][bn][f] = s*(x - sum_k w_k x[idx_k])
// ---------------------------------------------------------------------------
__global__ void lap1_all_kernel(const uint8_t* __restrict__ x, const int* __restrict__ idx,
        const float* __restrict__ w, const float* __restrict__ s,
        float* __restrict__ t1, int t0, int F){
  int blk = blockIdx.x; int f = threadIdx.x;
  int bn = blk % (NB*NN); int tt = blk / (NB*NN);
  int b = bn >> 10; int n = bn & (NN-1); int t = t0 + tt;
  __shared__ int nidx[KNN]; __shared__ float nw[KNN]; __shared__ float sv;
  if (f < KNN){ nidx[f] = idx[(size_t)bn*KNN+f]; nw[f] = w[(size_t)bn*KNN+f]; }
  if (f == 0) sv = s[bn];
  __syncthreads();
  const uint8_t* xb = x + ((size_t)(b*NT + t)*NN)*F;
  float acc = 0.0f;
  for (int k=0;k<KNN;k++)
    acc = fmaf(nw[k], (float)xb[(size_t)nidx[k]*F + f], acc);
  float xv = (float)xb[(size_t)n*F + f];
  t1[((size_t)tt*(NB*NN) + bn)*F + f] = sv * (xv - acc);
}

// ---------------------------------------------------------------------------
// lap2: t2 = 2*(s*(t1 - sum_k w_k t1[idx_k])) - x
// ---------------------------------------------------------------------------
__global__ void lap2_all_kernel(const uint8_t* __restrict__ x, const float* __restrict__ t1,
        const int* __restrict__ idx, const float* __restrict__ w, const float* __restrict__ s,
        float* __restrict__ t2, int t0, int F){
  int blk = blockIdx.x; int f = threadIdx.x;
  int bn = blk % (NB*NN); int tt = blk / (NB*NN);
  int b = bn >> 10; int n = bn & (NN-1); int t = t0 + tt;
  __shared__ int nidx[KNN]; __shared__ float nw[KNN]; __shared__ float sv;
  if (f < KNN){ nidx[f] = idx[(size_t)bn*KNN+f]; nw[f] = w[(size_t)bn*KNN+f]; }
  if (f == 0) sv = s[bn];
  __syncthreads();
  const float* t1b = t1 + ((size_t)tt*(NB*NN) + (size_t)b*NN)*F;
  float acc = 0.0f;
  for (int k=0;k<KNN;k++)
    acc = fmaf(nw[k], t1b[(size_t)nidx[k]*F + f], acc);
  float tv = t1[((size_t)tt*(NB*NN) + bn)*F + f];
  float lapv = sv * (tv - acc);
  const uint8_t* xb = x + ((size_t)(b*NT + t)*NN)*F;
  float xv = (float)xb[(size_t)n*F + f];
  t2[((size_t)tt*(NB*NN) + bn)*F + f] = 2.0f * lapv - xv;
}

// ---------------------------------------------------------------------------
// Chebyshev conv as f32 tile GEMM over rows = [tt][bn] (M = 4096*tc).
// A = [x | t1 | t2] (K = 3F), Wc: [3F][G].  k-loop strictly ascending so each
// output's fma chain is bit-identical to the sequential reference chain.
// Block: BM=64 x BN cols, 256 threads, thread tile TM=4 x TN.
// ---------------------------------------------------------------------------
template<int F, int G, int BN, int TN>
__global__ __launch_bounds__(256) void conv_gemm_kernel(const uint8_t* __restrict__ x,
        const float* __restrict__ t1, const float* __restrict__ t2,
        const float* __restrict__ W, float* __restrict__ abuf, int t0){
  constexpr int BM = 64, BK = 16, TM = 4;
  constexpr int NTX = BN / TN;               // 16
  constexpr int LDA = BM + 4;                // 68
  constexpr int LDB = BN + 4;                // 68 / 132
  __shared__ float As[BK * LDA];
  __shared__ float Ws[BK * LDB];

  const int tid = threadIdx.x;
  const int tx = tid % NTX, ty = tid / NTX;
  const int row0 = blockIdx.x * BM;
  const int g0 = blockIdx.y * BN;

  // A-load mapping: each thread loads 4 consecutive k for one row
  const int arow = tid >> 2;                 // 0..63
  const int akg  = (tid & 3) * 4;            // 0,4,8,12
  const int grow = row0 + arow;
  const int tt_a = grow / (NB*NN);
  const int bn_a = grow % (NB*NN);
  const int b_a = bn_a >> 10, n_a = bn_a & (NN-1);
  const uint8_t* xrow  = x  + ((size_t)(b_a*NT + t0 + tt_a)*NN + n_a)*F;
  const float*   t1row = t1 + (size_t)grow * F;
  const float*   t2row = t2 + (size_t)grow * F;

  float acc[TM][TN];
  #pragma unroll
  for (int r=0;r<TM;r++)
    #pragma unroll
    for (int c=0;c<TN;c++) acc[r][c] = 0.0f;

  for (int s = 0; s < 3; ++s){
    for (int f0 = 0; f0 < F; f0 += BK){
      // --- stage A chunk ---
      if (s == 0){
        uchar4 u = *(const uchar4*)(xrow + f0 + akg);
        As[(akg+0)*LDA + arow] = (float)u.x;
        As[(akg+1)*LDA + arow] = (float)u.y;
        As[(akg+2)*LDA + arow] = (float)u.z;
        As[(akg+3)*LDA + arow] = (float)u.w;
      } else {
        const float* src = ((s==1) ? t1row : t2row) + f0 + akg;
        float4 v = *(const float4*)src;
        As[(akg+0)*LDA + arow] = v.x;
        As[(akg+1)*LDA + arow] = v.y;
        As[(akg+2)*LDA + arow] = v.z;
        As[(akg+3)*LDA + arow] = v.w;
      }
      // --- stage W chunk ---
      const float* Wsrc = W + ((size_t)(s*F + f0))*G + g0;
      #pragma unroll
      for (int e = 0; e < (BK*BN)/(256*4); ++e){
        int idx = tid + e*256;
        int wk = idx / (BN/4);
        int wg = (idx % (BN/4))*4;
        *(float4*)&Ws[wk*LDB + wg] = *(const float4*)(Wsrc + (size_t)wk*G + wg);
      }
      __syncthreads();
      // --- compute ---
      #pragma unroll
      for (int k = 0; k < BK; ++k){
        float a[TM];
        *(float4*)a = *(const float4*)&As[k*LDA + ty*TM];
        float wv[TN];
        #pragma unroll
        for (int c = 0; c < TN; c += 4)
          *(float4*)&wv[c] = *(const float4*)&Ws[k*LDB + tx*TN + c];
        #pragma unroll
        for (int r=0;r<TM;r++)
          #pragma unroll
          for (int c=0;c<TN;c++)
            acc[r][c] = fmaf(a[r], wv[c], acc[r][c]);
      }
      __syncthreads();
    }
  }
  // epilogue: raw GEMM result (bias added in LIF, preserving order)
  #pragma unroll
  for (int r=0;r<TM;r++){
    float* dst = abuf + (size_t)(row0 + ty*TM + r)*G + g0 + tx*TN;
    #pragma unroll
    for (int c=0;c<TN;c+=4)
      *(float4*)(dst + c) = *(float4*)&acc[r][c];
  }
}

// ---------------------------------------------------------------------------
// LIF scan: one thread per (bn,g); t-loop in registers; bias added here in the
// exact reference order: a = gemm + b; v = decay*v + a; dual-threshold reset.
// ---------------------------------------------------------------------------
__global__ void lif_kernel(const float* __restrict__ abuf, const float* __restrict__ bias,
        float* __restrict__ vbuf, uint8_t* __restrict__ out, int t0, int tc, int G, float decay){
  int id = blockIdx.x*blockDim.x + threadIdx.x;
  if (id >= NB*NN*G) return;
  int g = id % G;
  int bn = id / G;
  int b = bn >> 10, n = bn & (NN-1);
  float v = (t0 == 0) ? 0.0f : vbuf[id];
  float bg = bias[g];
  for (int tt=0; tt<tc; ++tt){
    float a = abuf[((size_t)tt*(NB*NN) + bn)*G + g] + bg;
    float vn = decay * v + a;
    float sp  = ((vn - 1.0f) >= 0.0f) ? 1.0f : 0.0f;
    float snk = ((-1.0f - vn) >= 0.0f) ? 1.0f : 0.0f;
    vn = vn - sp * 1.0f;
    vn = vn - snk * (-1.0f);
    v = vn;
    uint8_t* ob = out + ((size_t)(b*NT + t0 + tt)*NN + n)*((size_t)2*G);
    ob[g]   = (uint8_t)sp;
    ob[G+g] = (uint8_t)snk;
  }
  if (t0 + tc < NT) vbuf[id] = v;
}

// ---------------------------------------------------------------------------
// Pool stage 1: integer spike counts (exact, order-independent)
// ---------------------------------------------------------------------------
__global__ void pool_partial_kernel(const uint8_t* __restrict__ sp, uint32_t* __restrict__ partial){
  int b = blockIdx.x >> 6;
  int chunk = blockIdx.x & 63;
  int n0 = chunk * 16;
  int u = threadIdx.x;                      // 0..127
  uint32_t c0=0,c1=0,c2=0,c3=0;
  for (int t=0;t<NT;t++){
    for (int n=0;n<16;n++){
      const uint32_t* rowp = (const uint32_t*)(sp + ((size_t)(b*NT+t)*NN + n0+n)*512);
      uint32_t wv = rowp[u];
      c0 += wv & 0xffu;
      c1 += (wv >> 8) & 0xffu;
      c2 += (wv >> 16) & 0xffu;
      c3 += wv >> 24;
    }
  }
  uint32_t* op = partial + (size_t)blockIdx.x*512 + u*4;
  op[0]=c0; op[1]=c1; op[2]=c2; op[3]=c3;
}

__global__ __launch_bounds__(512) void finalize_head_kernel(const uint32_t* __restrict__ partial,
        const float* __restrict__ roW, const float* __restrict__ rob, float* __restrict__ out){
  int b = blockIdx.x;
  int f = threadIdx.x;
  __shared__ float pooled[512];
  uint32_t cnt = 0;
  for (int ch=0; ch<64; ch++)
    cnt += partial[((size_t)(b*64+ch))*512 + f];
  pooled[f] = (float)cnt / 10.0f / 1024.0f;
  __syncthreads();
  if (f < 40){
    float acc = 0.0f;
    for (int k=0;k<512;k++)
      acc = fmaf(pooled[k], roW[k*40+f], acc);
    out[b*40 + f] = acc + rob[f];
  }
}

// ---------------------------------------------------------------------------
extern "C" void kernel_launch(void* const* d_in, const int* in_sizes, int n_in,
                              void* d_out, int out_size, void* d_ws, size_t ws_size,
                              hipStream_t stream) {
  const float* pc   = (const float*)d_in[0];
  const float* encW = (const float*)d_in[1];
  const float* encB = (const float*)d_in[2];
  const float* W0   = (const float*)d_in[3];
  const float* b0   = (const float*)d_in[4];
  const float* W1   = (const float*)d_in[5];
  const float* b1   = (const float*)d_in[6];
  const float* W2   = (const float*)d_in[7];
  const float* b2   = (const float*)d_in[8];
  const float* roW  = (const float*)d_in[9];
  const float* rob  = (const float*)d_in[10];
  float* outp = (float*)d_out;

  char* p = (char*)d_ws;
  auto alloc = [&](size_t bytes)->char*{
    char* r = p; p += (bytes + 255) & ~(size_t)255; return r;
  };
  int*      idxb   = (int*)     alloc((size_t)NB*NN*KNN*4);
  float*    wb     = (float*)   alloc((size_t)NB*NN*KNN*4);
  float*    sb     = (float*)   alloc((size_t)NB*NN*4);
  float*    rates  = (float*)   alloc((size_t)NB*NN*64*4);
  float*    vbuf   = (float*)   alloc((size_t)NB*NN*256*4);
  uint32_t* partial= (uint32_t*)alloc((size_t)NB*64*512*4);
  uint8_t*  bufA   = (uint8_t*) alloc((size_t)NB*NT*NN*512);
  uint8_t*  bufB   = (uint8_t*) alloc((size_t)NB*NT*NN*512);

  // timestep chunking: t1 + t2 + abuf per timestep (worst case F=256)
  size_t used = (size_t)(p - (char*)d_ws);
  size_t per_t = (size_t)NB*NN*256*4*3;
  int TC = 1;
  if (ws_size > used + per_t){
    size_t tcc = (ws_size - used) / per_t;
    TC = (tcc >= NT) ? NT : (int)tcc;
    if (TC < 1) TC = 1;
  }
  float* t1b  = (float*)alloc((size_t)NB*(size_t)TC*NN*256*4);
  float* t2b  = (float*)alloc((size_t)NB*(size_t)TC*NN*256*4);
  float* abuf = (float*)alloc((size_t)NB*(size_t)TC*NN*256*4);

  graph_kernel<<<NB*NN, 256, 0, stream>>>(pc, idxb, wb, sb);
  enc_kernel<<<(NB*NN*64 + 255)/256, 256, 0, stream>>>(pc, encW, encB, rates);
  {
    const uint32_t H = (uint32_t)(NB*NT*NN*64) / 2u;
    poisson_kernel<<<(H + 255)/256, 256, 0, stream>>>(rates, bufA);
  }

  float decay = expf(-1.0f / 20.0f);

  uint8_t* xin  = bufA;
  uint8_t* xout = bufB;
  for (int l=0; l<3; l++){
    int F = (l==0)?64:(l==1)?128:256;
    int G = F;
    const float* Wc = (l==0)?W0:(l==1)?W1:W2;
    const float* bc = (l==0)?b0:(l==1)?b1:b2;
    for (int t0=0; t0<NT; t0+=TC){
      int tc = (NT - t0 < TC) ? (NT - t0) : TC;
      int M = NB*NN*tc;
      lap1_all_kernel<<<NB*NN*tc, F, 0, stream>>>(xin, idxb, wb, sb, t1b, t0, F);
      lap2_all_kernel<<<NB*NN*tc, F, 0, stream>>>(xin, t1b, idxb, wb, sb, t2b, t0, F);
      if (l==0){
        dim3 grid(M/64, 1);
        conv_gemm_kernel<64,64,64,4><<<grid, 256, 0, stream>>>(xin, t1b, t2b, Wc, abuf, t0);
      } else if (l==1){
        dim3 grid(M/64, 2);
        conv_gemm_kernel<128,128,64,4><<<grid, 256, 0, stream>>>(xin, t1b, t2b, Wc, abuf, t0);
      } else {
        dim3 grid(M/64, 2);
        conv_gemm_kernel<256,256,128,8><<<grid, 256, 0, stream>>>(xin, t1b, t2b, Wc, abuf, t0);
      }
      lif_kernel<<<(NB*NN*G + 255)/256, 256, 0, stream>>>(abuf, bc, vbuf, xout, t0, tc, G, decay);
    }
    uint8_t* tmp = xin; xin = xout; xout = tmp;
  }

  pool_partial_kernel<<<NB*64, 128, 0, stream>>>(xin, partial);
  finalize_head_kernel<<<NB, 512, 0, stream>>>(partial, roW, rob, outp);
}